// Round 10
// baseline (326.893 us; speedup 1.0000x reference)
//
#include <hip/hip_runtime.h>
#include <stdint.h>

// Problem constants (match reference)
#define SLAB 8192    // SL
#define SUNL 16384   // SU
#define DIMX 1024
#define HID1 2048
#define HID2 512
#define KTRIES 8
#define MTOT (SLAB + SUNL)   // 24576

typedef __attribute__((ext_vector_type(8))) short bf16x8;    // 8 bf16 = 4 VGPRs
typedef __attribute__((ext_vector_type(8))) unsigned short u16x8;
typedef __attribute__((ext_vector_type(4))) float f32x4;

// fp32 -> bf16 round-to-nearest-even
__device__ __forceinline__ unsigned short f2bf(float f) {
  union { float f; uint32_t u; } c; c.f = f;
  return (unsigned short)((c.u + 0x7fffu + ((c.u >> 16) & 1u)) >> 16);
}

// async global->LDS, 16B per lane; lds dest = wave-uniform base + lane*16
__device__ __forceinline__ void async16(const void* g, void* l) {
  __builtin_amdgcn_global_load_lds(
      (const __attribute__((address_space(1))) unsigned int*)g,
      (__attribute__((address_space(3))) unsigned int*)l,
      16, 0, 0);
}

// ---------------------------------------------------------------------------
// Threefry2x32 (JAX-compatible, 20 rounds)
// ---------------------------------------------------------------------------
struct U2 { uint32_t x, y; };

__device__ __forceinline__ U2 threefry(uint32_t k0, uint32_t k1, uint32_t x0, uint32_t x1) {
  uint32_t ks2 = k0 ^ k1 ^ 0x1BD11BDAu;
  x0 += k0; x1 += k1;
#define TF_R(r) { x0 += x1; x1 = (x1 << (r)) | (x1 >> (32 - (r))); x1 ^= x0; }
  TF_R(13) TF_R(15) TF_R(26) TF_R(6)
  x0 += k1; x1 += ks2 + 1u;
  TF_R(17) TF_R(29) TF_R(16) TF_R(24)
  x0 += ks2; x1 += k0 + 2u;
  TF_R(13) TF_R(15) TF_R(26) TF_R(6)
  x0 += k0; x1 += k1 + 3u;
  TF_R(17) TF_R(29) TF_R(16) TF_R(24)
  x0 += k1; x1 += ks2 + 4u;
  TF_R(13) TF_R(15) TF_R(26) TF_R(6)
  x0 += ks2; x1 += k0 + 5u;
#undef TF_R
  return {x0, x1};
}

// ---------------------------------------------------------------------------
// prep_kernel: one launch for cast(X_l|X_u), transpose-cast W1, W2, and pairs.
// R10: cast = 8 floats/thread -> ONE 16B ushort8 store (was 8B ushort4 —
// half-width writes on a 50 MB stream). Cast grid halves.
// ---------------------------------------------------------------------------
#define XL_BLOCKS (SLAB * DIMX / 8 / 256)           // 4096
#define CAST_BLOCKS (MTOT * DIMX / 8 / 256)         // 12288
#define T1_NBX (HID1 / 32)                          // 64
#define T1_BLOCKS ((HID1 / 32) * (DIMX / 32))       // 2048
#define T2_NBX (HID2 / 32)                          // 16
#define T2_BLOCKS ((HID2 / 32) * (HID1 / 32))       // 1024
#define PAIR_BLOCKS (SUNL / 256)                    // 64
#define PREP_BLOCKS (CAST_BLOCKS + T1_BLOCKS + T2_BLOCKS + PAIR_BLOCKS)

__global__ __launch_bounds__(256) void prep_kernel(
    const float* __restrict__ Xl, const float* __restrict__ Xu,
    const float* __restrict__ W1, const float* __restrict__ W2,
    const float* __restrict__ y_l, const float* __restrict__ y_u,
    unsigned short* __restrict__ X_bf, unsigned short* __restrict__ W1T,
    unsigned short* __restrict__ W2T,
    int* __restrict__ ia, int* __restrict__ ib, float* __restrict__ kv)
{
  __shared__ float t[32][33];
  int b = blockIdx.x;
  int tid = threadIdx.x;

  if (b < CAST_BLOCKS) {
    const float* src; size_t i, doff;
    if (b < XL_BLOCKS) { src = Xl; i = (size_t)b * 256 + tid; doff = 0; }
    else { src = Xu; i = (size_t)(b - XL_BLOCKS) * 256 + tid; doff = (size_t)SLAB * DIMX / 8; }
    float4 v0 = ((const float4*)src)[2 * i];
    float4 v1 = ((const float4*)src)[2 * i + 1];
    u16x8 o;
    o[0] = f2bf(v0.x); o[1] = f2bf(v0.y); o[2] = f2bf(v0.z); o[3] = f2bf(v0.w);
    o[4] = f2bf(v1.x); o[5] = f2bf(v1.y); o[6] = f2bf(v1.z); o[7] = f2bf(v1.w);
    ((u16x8*)X_bf)[doff + i] = o;
  } else if (b < CAST_BLOCKS + T1_BLOCKS + T2_BLOCKS) {
    const float* W; unsigned short* WT; int K, N, bx, by;
    if (b < CAST_BLOCKS + T1_BLOCKS) {
      int tb = b - CAST_BLOCKS;
      W = W1; WT = W1T; K = DIMX; N = HID1; bx = tb % T1_NBX; by = tb / T1_NBX;
    } else {
      int tb = b - CAST_BLOCKS - T1_BLOCKS;
      W = W2; WT = W2T; K = HID1; N = HID2; bx = tb % T2_NBX; by = tb / T2_NBX;
    }
    int k0 = by * 32, n0 = bx * 32;
    int tx = tid & 31, ty = tid >> 5;
#pragma unroll
    for (int i = 0; i < 32; i += 8)
      t[ty + i][tx] = W[(size_t)(k0 + ty + i) * N + n0 + tx];
    __syncthreads();
#pragma unroll
    for (int i = 0; i < 32; i += 8)
      WT[(size_t)(n0 + ty + i) * K + k0 + tx] = f2bf(t[tx][ty + i]);
  } else {
    // pair sampling (verified R1: partitionable threefry, bits1^bits2, &8191)
    int r = (b - CAST_BLOCKS - T1_BLOCKS - T2_BLOCKS) * 256 + tid;
    U2 ka  = threefry(0u, 42u, 0u, 0u);
    U2 kb  = threefry(0u, 42u, 0u, 1u);
    U2 k2a = threefry(ka.x, ka.y, 0u, 1u);
    U2 k2b = threefry(kb.x, kb.y, 0u, 1u);
    int iav[KTRIES], ibv[KTRIES];
#pragma unroll
    for (int c = 0; c < KTRIES; ++c) {
      uint32_t tt = (uint32_t)(r * KTRIES + c);
      U2 oa = threefry(k2a.x, k2a.y, 0u, tt);
      U2 ob = threefry(k2b.x, k2b.y, 0u, tt);
      iav[c] = (int)((oa.x ^ oa.y) & (SLAB - 1));
      ibv[c] = (int)((ob.x ^ ob.y) & (SLAB - 1));
    }
    int a = iav[0], bb2 = ibv[0];
#pragma unroll
    for (int c = 0; c < KTRIES; ++c) {
      if (iav[c] != ibv[c] && y_l[iav[c]] != y_l[ibv[c]]) { a = iav[c]; bb2 = ibv[c]; break; }
    }
    float ya = y_l[a], yb = y_l[bb2];
    ia[r] = a; ib[r] = bb2; kv[r] = (y_u[r] - yb) / (ya - yb);
  }
}

// ---------------------------------------------------------------------------
// bf16 MFMA GEMM, 256x256 tile, BK=64 (two BK=32 sub-steps), R10 =
// R9 (best: 106.5us GEMM1, compiler-scheduled) + T5 setprio on MFMA
// clusters (m218b: structure-conditional gain on phase-split schedules;
// ~0 risk per m190).
//   - Register-ceiling diagnosis (R9 counters): VGPR 120 vs hard cap 128
//     (256 unified - 128 AGPR acc). MfmaUtil 42% + LDS ~50% ~ fully
//     serial pipes; overlap would need deeper read buffering = more live
//     frags = over the cap (R3/R4 spill). 128x64 wave tile is forced
//     (smaller -> LDS-bound, larger -> AGPR cap), so ~42% is the
//     register-budget ceiling for this structure.
//   - Kept invariants (verified R7/R9):
//     * lgkmcnt(0)+"memory" before BAR1 (cross-wave read-drain before
//       staging overwrites cur).
//     * counted vmcnt(8) once per tile + BAR2 (DMA residency ledger:
//       queue = S@t-1(8)+S@t(8) -> drains S@t-1 -> t+1 resident).
//       Prologue 16 calls, vmcnt(8) = tile0 resident. Tail vmcnt(0)@NT-2.
//     * q4'-rotation + pre-issued {a0,b0} program order (hint only).
//   - LDS 128 KB, swizzle slot = c16 ^ (row&7) (0 conflicts measured),
//     staging source pre-swizzled (rule #21). Epilogue j-innermost.
//   - Per-acc-element K order ascending -> bit-identical output.
// ---------------------------------------------------------------------------
#define GROUP_M 8
#define MFMA_B16(a, b, c) __builtin_amdgcn_mfma_f32_16x16x32_bf16(a, b, c, 0, 0, 0)

template<bool QP, bool BARS, bool ST, int VMC, bool PRE>
__device__ __forceinline__ void ksub(
    const unsigned short* AsB, const unsigned short* BsB,   // read buf
    unsigned short* AsS, unsigned short* BsS,               // staging dest
    const unsigned short* AsP, const unsigned short* BsP,   // pre-issue buf
    const unsigned short* gA, const unsigned short* gB,
    int kk2, int K, int ldst,
    int ofsA, int ofsB, int ofsAp, int ofsBp,
    bf16x8 (&ha0)[4], bf16x8 (&hb0)[2],   // in: this sub a0,b0 (pre-issued)
    bf16x8 (&na0)[4], bf16x8 (&nb0)[2],   // out: next sub a0,b0
    bf16x8 (&ca1)[4], bf16x8 (&cb1)[2],   // in: prev sub a1,b1 (q4')
    bf16x8 (&ta1)[4], bf16x8 (&tb1)[2],   // out: this sub a1,b1
    f32x4 (&acc)[8][4])
{
  // issue b1 reads; q4'(prev) runs on registers meanwhile
#pragma unroll
  for (int j = 0; j < 2; ++j)
    tb1[j] = *(const bf16x8*)(BsB + ofsB + (j + 2) * 1024);
  if (QP) {
    __builtin_amdgcn_s_setprio(1);
#pragma unroll
    for (int i = 0; i < 4; ++i)
#pragma unroll
      for (int j = 0; j < 2; ++j)
        acc[i + 4][j + 2] = MFMA_B16(ca1[i], cb1[j], acc[i + 4][j + 2]);
    __builtin_amdgcn_s_setprio(0);
  }
  // q1: a0 x b0 (operands pre-issued last sub; compiler inserts exact waits)
  __builtin_amdgcn_s_setprio(1);
#pragma unroll
  for (int i = 0; i < 4; ++i)
#pragma unroll
    for (int j = 0; j < 2; ++j)
      acc[i][j] = MFMA_B16(ha0[i], hb0[j], acc[i][j]);
  __builtin_amdgcn_s_setprio(0);

  // issue a1 reads; q2: a0 x b1
#pragma unroll
  for (int i = 0; i < 4; ++i)
    ta1[i] = *(const bf16x8*)(AsB + ofsA + (i + 4) * 1024);
  __builtin_amdgcn_s_setprio(1);
#pragma unroll
  for (int i = 0; i < 4; ++i)
#pragma unroll
    for (int j = 0; j < 2; ++j)
      acc[i][j + 2] = MFMA_B16(ha0[i], tb1[j], acc[i][j + 2]);
  __builtin_amdgcn_s_setprio(0);

  if (BARS) {
    // all cur-buf reads must be DRAINED (not just issued) before any
    // wave's staging overwrites cur -- cross-wave, compiler can't derive
    asm volatile("s_waitcnt lgkmcnt(0)" ::: "memory");
    __builtin_amdgcn_s_barrier();              // BAR1
  }
  if (ST) {
#pragma unroll
    for (int c = 0; c < 4; ++c) {
      async16(gA + (size_t)(c * 64) * K + kk2, AsS + c * 4096 + ldst);
      async16(gB + (size_t)(c * 64) * K + kk2, BsS + c * 4096 + ldst);
    }
  }
  // q3: a1 x b0 (overlaps staging issue/DMA)
  __builtin_amdgcn_s_setprio(1);
#pragma unroll
  for (int i = 0; i < 4; ++i)
#pragma unroll
    for (int j = 0; j < 2; ++j)
      acc[i + 4][j] = MFMA_B16(ta1[i], hb0[j], acc[i + 4][j]);
  __builtin_amdgcn_s_setprio(0);
  if (VMC == 8)      asm volatile("s_waitcnt vmcnt(8)" ::: "memory");
  else if (VMC == 0) asm volatile("s_waitcnt vmcnt(0)" ::: "memory");
  if (BARS) __builtin_amdgcn_s_barrier();      // BAR2: tile t+1 resident

  // pre-issue next sub's a0,b0 (drain under next q4'/q1)
  if (PRE) {
#pragma unroll
    for (int i = 0; i < 4; ++i)
      na0[i] = *(const bf16x8*)(AsP + ofsAp + i * 1024);
#pragma unroll
    for (int j = 0; j < 2; ++j)
      nb0[j] = *(const bf16x8*)(BsP + ofsBp + j * 1024);
  }
}

template<int OUT_BF16, int RELU>
__global__ __launch_bounds__(512, 2) void gemm_bt_256(
    const unsigned short* __restrict__ A,   // [M][K] bf16
    const unsigned short* __restrict__ Bt,  // [N][K] bf16
    const float* __restrict__ bias,         // [N] fp32
    void* __restrict__ C0, void* __restrict__ C1, int Msplit,
    int M, int N, int K)
{
  __shared__ unsigned short As[2][16384];   // 2 x 256x64 bf16 = 64 KB
  __shared__ unsigned short Bs[2][16384];   // 64 KB

  const int tid  = threadIdx.x;
  const int wave = tid >> 6;
  const int lane = tid & 63;

  // L2 block swizzle (m-panels of 256 rows)
  const int nbx = N >> 8;
  const int gsize = nbx * GROUP_M;
  const int grp = blockIdx.x / gsize, within = blockIdx.x % gsize;
  const int m0 = (grp * GROUP_M + (within % GROUP_M)) << 8;
  const int n0 = (within / GROUP_M) << 8;

  const int wm = (wave >> 2) << 7;   // 0 / 128
  const int wn = (wave & 3) << 6;    // 0 / 64 / 128 / 192

  // staging lane geometry: call = 512 lanes x 16B = 64 rows x 128B
  // pre-swizzled chunk (R2-verified, 0 conflicts): key = row&7 over 8 chunks
  const int srow   = tid >> 3;                  // row within call (0..63)
  const int schunk = (tid & 7) ^ (srow & 7);    // pre-swizzled 16B chunk
  const unsigned short* gA = A  + (size_t)(m0 + srow) * K + schunk * 8;
  const unsigned short* gB = Bt + (size_t)(n0 + srow) * K + schunk * 8;
  const int ldst = wave << 9;                   // wave LDS slice (ushorts)

  // fragment read geometry: lane (fr,q), sub k-half s: chunk = q + 4s,
  // slot = chunk ^ (fr&7); sub1 offset = sub0 ^ 32 (ushorts)
  const int fr = lane & 15, q = lane >> 4;
  const int cs0 = (q ^ (fr & 7)) << 3;
  const int ofsA0 = ((wm + fr) << 6) + cs0;
  const int ofsB0 = ((wn + fr) << 6) + cs0;
  const int ofsA1 = ofsA0 ^ 32;
  const int ofsB1 = ofsB0 ^ 32;

  f32x4 acc[8][4] = {};
  bf16x8 a0A[4], b0A[2], a0B[4], b0B[2];   // head sets (pre-issued a0,b0)
  bf16x8 a1A[4], b1A[2], a1B[4], b1B[2];   // tail sets (q4 carry a1,b1)

  unsigned short* A0p = &As[0][0]; unsigned short* B0p = &Bs[0][0];
  unsigned short* A1p = &As[1][0]; unsigned short* B1p = &Bs[1][0];

  // prologue: stage tile0 -> buf0 (8 calls), tile1 -> buf1 (8 calls);
  // vmcnt(8) = tile0 resident, tile1 in flight (ledger invariant).
#pragma unroll
  for (int c = 0; c < 4; ++c) {
    async16(gA + (size_t)(c * 64) * K,      A0p + c * 4096 + ldst);
    async16(gB + (size_t)(c * 64) * K,      B0p + c * 4096 + ldst);
  }
#pragma unroll
  for (int c = 0; c < 4; ++c) {
    async16(gA + (size_t)(c * 64) * K + 64, A1p + c * 4096 + ldst);
    async16(gB + (size_t)(c * 64) * K + 64, B1p + c * 4096 + ldst);
  }
  asm volatile("s_waitcnt vmcnt(8)" ::: "memory");
  __builtin_amdgcn_s_barrier();
  // pre-issue a0,b0 of tile0 sub0 (buf0)
#pragma unroll
  for (int i = 0; i < 4; ++i)
    a0A[i] = *(const bf16x8*)(A0p + ofsA0 + i * 1024);
#pragma unroll
  for (int j = 0; j < 2; ++j)
    b0A[j] = *(const bf16x8*)(B0p + ofsB0 + j * 1024);

  const int NT = K >> 6;   // 16 (GEMM1) or 32 (GEMM2); even, >= 6

  // t = 0 (buf0): sub0 has no q4' yet
  ksub<false, false, false, -1, true>(A0p, B0p, A0p, B0p, A0p, B0p, gA, gB,
      0, K, ldst, ofsA0, ofsB0, ofsA1, ofsB1,
      a0A, b0A, a0B, b0B, a1B, b1B, a1A, b1A, acc);
  ksub<true, true, true, 8, true>(A0p, B0p, A0p, B0p, A1p, B1p, gA, gB,
      2 * 64, K, ldst, ofsA1, ofsB1, ofsA0, ofsB0,
      a0B, b0B, a0A, b0A, a1A, b1A, a1B, b1B, acc);

  // t = 1 .. NT-4 in pairs (buf1, buf0)
#pragma unroll 1
  for (int t = 1; t <= NT - 4; t += 2) {
    ksub<true, false, false, -1, true>(A1p, B1p, A1p, B1p, A1p, B1p, gA, gB,
        0, K, ldst, ofsA0, ofsB0, ofsA1, ofsB1,
        a0A, b0A, a0B, b0B, a1B, b1B, a1A, b1A, acc);
    ksub<true, true, true, 8, true>(A1p, B1p, A1p, B1p, A0p, B0p, gA, gB,
        (t + 2) * 64, K, ldst, ofsA1, ofsB1, ofsA0, ofsB0,
        a0B, b0B, a0A, b0A, a1A, b1A, a1B, b1B, acc);
    ksub<true, false, false, -1, true>(A0p, B0p, A0p, B0p, A0p, B0p, gA, gB,
        0, K, ldst, ofsA0, ofsB0, ofsA1, ofsB1,
        a0A, b0A, a0B, b0B, a1B, b1B, a1A, b1A, acc);
    ksub<true, true, true, 8, true>(A0p, B0p, A0p, B0p, A1p, B1p, gA, gB,
        (t + 3) * 64, K, ldst, ofsA1, ofsB1, ofsA0, ofsB0,
        a0B, b0B, a0A, b0A, a1A, b1A, a1B, b1B, acc);
  }
  // t = NT-3 (buf1): full, stages tile NT-1
  ksub<true, false, false, -1, true>(A1p, B1p, A1p, B1p, A1p, B1p, gA, gB,
      0, K, ldst, ofsA0, ofsB0, ofsA1, ofsB1,
      a0A, b0A, a0B, b0B, a1B, b1B, a1A, b1A, acc);
  ksub<true, true, true, 8, true>(A1p, B1p, A1p, B1p, A0p, B0p, gA, gB,
      (NT - 1) * 64, K, ldst, ofsA1, ofsB1, ofsA0, ofsB0,
      a0B, b0B, a0A, b0A, a1A, b1A, a1B, b1B, acc);
  // t = NT-2 (buf0): no stage; vmcnt(0) -> tile NT-1 resident
  ksub<true, false, false, -1, true>(A0p, B0p, A0p, B0p, A0p, B0p, gA, gB,
      0, K, ldst, ofsA0, ofsB0, ofsA1, ofsB1,
      a0A, b0A, a0B, b0B, a1B, b1B, a1A, b1A, acc);
  ksub<true, true, false, 0, true>(A0p, B0p, A0p, B0p, A1p, B1p, gA, gB,
      0, K, ldst, ofsA1, ofsB1, ofsA0, ofsB0,
      a0B, b0B, a0A, b0A, a1A, b1A, a1B, b1B, acc);
  // t = NT-1 (buf1): no barriers/staging
  ksub<true, false, false, -1, true>(A1p, B1p, A1p, B1p, A1p, B1p, gA, gB,
      0, K, ldst, ofsA0, ofsB0, ofsA1, ofsB1,
      a0A, b0A, a0B, b0B, a1B, b1B, a1A, b1A, acc);
  ksub<true, false, false, -1, false>(A1p, B1p, A1p, B1p, A1p, B1p, gA, gB,
      0, K, ldst, ofsA1, ofsB1, ofsA0, ofsB0,
      a0B, b0B, a0A, b0A, a1A, b1A, a1B, b1B, acc);
  // final q4 of last sub (tail set B)
  __builtin_amdgcn_s_setprio(1);
#pragma unroll
  for (int i = 0; i < 4; ++i)
#pragma unroll
    for (int j = 0; j < 2; ++j)
      acc[i + 4][j + 2] = MFMA_B16(a1B[i], b1B[j], acc[i + 4][j + 2]);
  __builtin_amdgcn_s_setprio(0);

  // epilogue: bias + optional relu; per-block output select (tile-aligned)
  // C/D layout: col = lane&15, row = (lane>>4)*4 + reg   [m89/m91 verified]
  // j INNERMOST: each 128B output line completed in 4 consecutive stores
  void* Cb = (m0 < Msplit) ? C0 : C1;
  const int mbase = (m0 < Msplit) ? m0 : (m0 - Msplit);
  const int crow = mbase + wm + (lane >> 4) * 4;
  const int ccol = n0 + wn + (lane & 15);
  float bv[4];
#pragma unroll
  for (int j = 0; j < 4; ++j) bv[j] = bias[ccol + j * 16];
#pragma unroll
  for (int i = 0; i < 8; ++i) {
#pragma unroll
    for (int r = 0; r < 4; ++r) {
      size_t base = (size_t)(crow + i * 16 + r) * N + ccol;
#pragma unroll
      for (int j = 0; j < 4; ++j) {
        float v = acc[i][j][r] + bv[j];
        if (RELU) v = fmaxf(v, 0.0f);
        if (OUT_BF16) ((unsigned short*)Cb)[base + j * 16] = f2bf(v);
        else          ((float*)Cb)[base + j * 16] = v;
      }
    }
  }
}

// ---------------------------------------------------------------------------
// post_kernel: comb (blocks [0, SUNL/2)) + yhat (blocks [SUNL/2, +SLAB/4))
// ---------------------------------------------------------------------------
#define COMB_BLOCKS (SUNL / 2)              // 8192
#define YHAT_BLOCKS (SLAB / 4)              // 2048
#define POST_BLOCKS (COMB_BLOCKS + YHAT_BLOCKS)

__global__ __launch_bounds__(256) void post_kernel(
    const float* __restrict__ feat_l, const float* __restrict__ W3,
    const float* __restrict__ b3, const int* __restrict__ ia,
    const int* __restrict__ ib, const float* __restrict__ kv,
    float* __restrict__ out_comb, float* __restrict__ out_yhat)
{
  int b = blockIdx.x;
  if (b < COMB_BLOCKS) {
    int row = b * 2 + (threadIdx.x >> 7);
    int c = (threadIdx.x & 127) << 2;
    float k = kv[row];
    float km1 = 1.0f - k;
    float4 fa = *(const float4*)(feat_l + (size_t)ia[row] * HID2 + c);
    float4 fb = *(const float4*)(feat_l + (size_t)ib[row] * HID2 + c);
    float4 o;
    o.x = k * fa.x + km1 * fb.x;
    o.y = k * fa.y + km1 * fb.y;
    o.z = k * fa.z + km1 * fb.z;
    o.w = k * fa.w + km1 * fb.w;
    *(float4*)(out_comb + (size_t)row * HID2 + c) = o;
  } else {
    int wave = threadIdx.x >> 6;
    int lane = threadIdx.x & 63;
    int row = (b - COMB_BLOCKS) * 4 + wave;
    const float* f = feat_l + (size_t)row * HID2;
    float s = 0.f;
#pragma unroll
    for (int j = 0; j < HID2 / 64; ++j) s = fmaf(f[lane + j * 64], W3[lane + j * 64], s);
#pragma unroll
    for (int off = 32; off; off >>= 1) s += __shfl_down(s, off);
    if (lane == 0) out_yhat[row] = s + b3[0];
  }
}

// ---------------------------------------------------------------------------
extern "C" void kernel_launch(void* const* d_in, const int* in_sizes, int n_in,
                              void* d_out, int out_size, void* d_ws, size_t ws_size,
                              hipStream_t stream)
{
  const float* X_l = (const float*)d_in[0];
  const float* y_l = (const float*)d_in[1];
  const float* X_u = (const float*)d_in[2];
  const float* y_u = (const float*)d_in[3];
  const float* W1  = (const float*)d_in[4];
  const float* b1  = (const float*)d_in[5];
  const float* W2  = (const float*)d_in[6];
  const float* b2  = (const float*)d_in[7];
  const float* W3  = (const float*)d_in[8];
  const float* b3  = (const float*)d_in[9];

  float* out_featu = (float*)d_out;
  float* out_comb  = out_featu + (size_t)SUNL * HID2;
  float* out_yhat  = out_comb + (size_t)SUNL * HID2;

  // Workspace (~174 MB): X_bf = [Xl|Xu] contig, H_bf = [Hl|Hu] contig
  unsigned short* X_bf  = (unsigned short*)d_ws;                 // [24576][1024]
  unsigned short* W1T   = X_bf + (size_t)MTOT * DIMX;
  unsigned short* W2T   = W1T + (size_t)HID1 * DIMX;
  unsigned short* H_bf  = W2T + (size_t)HID2 * HID1;             // [24576][2048]
  float* feat_l = (float*)(H_bf + (size_t)MTOT * HID1);
  int*   ai = (int*)(feat_l + (size_t)SLAB * HID2);
  int*   bi = ai + SUNL;
  float* kv = (float*)(bi + SUNL);

  prep_kernel<<<dim3(PREP_BLOCKS), dim3(256), 0, stream>>>(
      X_l, X_u, W1, W2, y_l, y_u, X_bf, W1T, W2T, ai, bi, kv);

  // layer 1 (merged l+u): H = relu(X @ W1 + b1) -> bf16  [768 blocks x 512]
  gemm_bt_256<1, 1><<<dim3((HID1 / 256) * (MTOT / 256)), dim3(512), 0, stream>>>(
      X_bf, W1T, b1, H_bf, H_bf, MTOT /*no split*/, MTOT, HID1, DIMX);

  // layer 2 (merged l+u): feat = relu(H @ W2 + b2) -> fp32, split dest [192 blocks]
  gemm_bt_256<0, 1><<<dim3((HID2 / 256) * (MTOT / 256)), dim3(512), 0, stream>>>(
      H_bf, W2T, b2, feat_l, out_featu, SLAB, MTOT, HID2, HID1);

  post_kernel<<<dim3(POST_BLOCKS), dim3(256), 0, stream>>>(
      feat_l, W3, b3, ai, bi, kv, out_comb, out_yhat);
}